// Round 6
// baseline (451.000 us; speedup 1.0000x reference)
//
#include <hip/hip_runtime.h>
#include <math.h>

// Problem constants (from reference)
#define NN 50000
#define NE 800000
#define NFEAT 128
#define NHID 64
#define NCLASS 16
#define NB_SCAN ((NN + 255) / 256)  // 196
#define ROWS_PER_GRP 6250           // NN / 8 XCD groups
#define SCHUNKS 392                 // scatter edge chunks; grid = 8*392
#define GB ((NN + 63) / 64)         // 782 row-tiles
#define NBH ((NN + 7) / 8)          // 6250 spmm blocks per feature-half

struct alignas(8) Edge {
    int c;
    float w;
};

// fp32 <-> bf16 helpers (RNE round)
__device__ inline unsigned short f2bf(float f) {
    unsigned u = __builtin_bit_cast(unsigned, f);
    u += 0x7fffu + ((u >> 16) & 1u);
    return (unsigned short)(u >> 16);
}
__device__ inline float bf2f(unsigned short h) {
    return __builtin_bit_cast(float, (unsigned)h << 16);
}

// ---------------- CSR build ----------------

__global__ __launch_bounds__(256) void hist_kernel(const int* __restrict__ row,
                                                   int* __restrict__ deg, int E) {
    int e = blockIdx.x * 256 + threadIdx.x;
    if (e < E) atomicAdd(&deg[row[e]], 1);
}

__global__ __launch_bounds__(256) void scan_sum_kernel(const int* __restrict__ deg,
                                                       int* __restrict__ blocksum, int n) {
    __shared__ int s[256];
    const int t = threadIdx.x;
    int i = blockIdx.x * 256 + t;
    s[t] = (i < n) ? deg[i] : 0;
    __syncthreads();
#pragma unroll
    for (int off = 128; off > 0; off >>= 1) {
        if (t < off) s[t] += s[t + off];
        __syncthreads();
    }
    if (t == 0) blocksum[blockIdx.x] = s[0];
}

__global__ __launch_bounds__(256) void scan_top_kernel(int* __restrict__ blocksum, int nb) {
    __shared__ int s[256];
    const int t = threadIdx.x;
    int v = (t < nb) ? blocksum[t] : 0;
    s[t] = v;
    __syncthreads();
    for (int off = 1; off < 256; off <<= 1) {
        int u = (t >= off) ? s[t - off] : 0;
        __syncthreads();
        s[t] += u;
        __syncthreads();
    }
    if (t < nb) blocksum[t] = s[t] - v;  // exclusive
}

__global__ __launch_bounds__(256) void scan_final_kernel(const int* __restrict__ deg,
                                                         const int* __restrict__ blocksum,
                                                         int* __restrict__ row_ptr,
                                                         int* __restrict__ cursor, int n) {
    __shared__ int s[256];
    const int t = threadIdx.x;
    int i = blockIdx.x * 256 + t;
    int d = (i < n) ? deg[i] : 0;
    s[t] = d;
    __syncthreads();
    for (int off = 1; off < 256; off <<= 1) {
        int u = (t >= off) ? s[t - off] : 0;
        __syncthreads();
        s[t] += u;
        __syncthreads();
    }
    int excl = blocksum[blockIdx.x] + s[t] - d;
    if (i < n) {
        row_ptr[i] = excl;
        cursor[i] = excl;
        if (i == n - 1) row_ptr[n] = excl + d;
    }
}

// XCD-partitioned scatter (round 3): block b -> row group b%8, edge chunk b/8.
__global__ __launch_bounds__(256) void scatter_part_kernel(const int* __restrict__ row,
                                                           const int* __restrict__ col,
                                                           const float* __restrict__ w,
                                                           int* __restrict__ cursor,
                                                           Edge* __restrict__ pairs, int E) {
    const int g = blockIdx.x & 7;
    const int chunk = blockIdx.x >> 3;
    const int CH = (E + SCHUNKS - 1) / SCHUNKS;
    const int lo = chunk * CH;
    const int hi = (lo + CH < E) ? lo + CH : E;
    for (int e = lo + threadIdx.x; e < hi; e += 256) {
        int r = row[e];
        if (r / ROWS_PER_GRP == g) {
            int pos = atomicAdd(&cursor[r], 1);
            Edge p;
            p.c = col[e];
            p.w = w[e];
            pairs[pos] = p;
        }
    }
}

// ---------------- Tiled GEMM: out[M,64] = in[M,K] @ W[K,64], bf16 or fp32 out ----------------
template <int K, bool BF16OUT>
__global__ __launch_bounds__(256) void gemm64_kernel(const float* __restrict__ in,
                                                     const float* __restrict__ Wg,
                                                     void* __restrict__ outv, int M) {
    constexpr int KC = 64;
    __shared__ float xs[KC][68];
    __shared__ float Ws[KC][64];
    const int t = threadIdx.x;
    const int tx = t % 16;
    const int ty = t / 16;
    const int r0 = blockIdx.x * 64;

    float acc[4][4];
#pragma unroll
    for (int i = 0; i < 4; i++)
#pragma unroll
        for (int j = 0; j < 4; j++) acc[i][j] = 0.f;

    for (int k0 = 0; k0 < K; k0 += KC) {
        for (int i = t * 4; i < KC * 64; i += 1024) {
            *(float4*)&Ws[i / 64][i % 64] = *(const float4*)&Wg[(size_t)k0 * 64 + i];
        }
        {
            const int r = t / 4;
            const int q = t % 4;
            const int gr = r0 + r;
#pragma unroll
            for (int i = 0; i < 4; i++) {
                int k = q * 16 + i * 4;
                float4 v;
                if (gr < M)
                    v = *(const float4*)&in[(size_t)gr * K + k0 + k];
                else
                    v = make_float4(0.f, 0.f, 0.f, 0.f);
                xs[k + 0][r] = v.x;
                xs[k + 1][r] = v.y;
                xs[k + 2][r] = v.z;
                xs[k + 3][r] = v.w;
            }
        }
        __syncthreads();
#pragma unroll 8
        for (int k = 0; k < KC; k++) {
            float4 xv = *(const float4*)&xs[k][ty * 4];
            float4 wv = *(const float4*)&Ws[k][tx * 4];
            acc[0][0] += xv.x * wv.x; acc[0][1] += xv.x * wv.y;
            acc[0][2] += xv.x * wv.z; acc[0][3] += xv.x * wv.w;
            acc[1][0] += xv.y * wv.x; acc[1][1] += xv.y * wv.y;
            acc[1][2] += xv.y * wv.z; acc[1][3] += xv.y * wv.w;
            acc[2][0] += xv.z * wv.x; acc[2][1] += xv.z * wv.y;
            acc[2][2] += xv.z * wv.z; acc[2][3] += xv.z * wv.w;
            acc[3][0] += xv.w * wv.x; acc[3][1] += xv.w * wv.y;
            acc[3][2] += xv.w * wv.z; acc[3][3] += xv.w * wv.w;
        }
        __syncthreads();
    }
#pragma unroll
    for (int i = 0; i < 4; i++) {
        int r = r0 + ty * 4 + i;
        if (r < M) {
            if (BF16OUT) {
                ushort4 u;
                u.x = f2bf(acc[i][0]);
                u.y = f2bf(acc[i][1]);
                u.z = f2bf(acc[i][2]);
                u.w = f2bf(acc[i][3]);
                *(ushort4*)&((unsigned short*)outv)[(size_t)r * 64 + tx * 4] = u;
            } else {
                float4 v;
                v.x = acc[i][0]; v.y = acc[i][1]; v.z = acc[i][2]; v.w = acc[i][3];
                *(float4*)&((float*)outv)[(size_t)r * 64 + tx * 4] = v;
            }
        }
    }
}

// ---------------- Small GEMM (layer 5): out[M,16] = in[M,64] @ W[64,16] ----------------
template <int K, int NOUT, int RPT>
__global__ __launch_bounds__(256) void gemm_kernel(const float* __restrict__ in,
                                                   const float* __restrict__ Wg,
                                                   float* __restrict__ out, int M) {
    __shared__ float Wl[K * NOUT];
    for (int i = threadIdx.x * 4; i < K * NOUT; i += 256 * 4) {
        *(float4*)&Wl[i] = *(const float4*)&Wg[i];
    }
    __syncthreads();

    constexpr int GROUPS = 256 / NOUT;
    constexpr int RPB = GROUPS * RPT;
    const int col = threadIdx.x % NOUT;
    const int grp = threadIdx.x / NOUT;
    const int r = blockIdx.x * RPB + grp * RPT;
    if (r >= M) return;

    float acc[RPT];
#pragma unroll
    for (int j = 0; j < RPT; j++) acc[j] = 0.f;

    const float* pr = in + (size_t)r * K;
#pragma unroll 2
    for (int k = 0; k < K; k += 4) {
        float w0 = Wl[(k + 0) * NOUT + col];
        float w1 = Wl[(k + 1) * NOUT + col];
        float w2 = Wl[(k + 2) * NOUT + col];
        float w3 = Wl[(k + 3) * NOUT + col];
#pragma unroll
        for (int j = 0; j < RPT; j++) {
            float4 xv = *(const float4*)(pr + j * K + k);
            acc[j] += xv.x * w0;
            acc[j] += xv.y * w1;
            acc[j] += xv.z * w2;
            acc[j] += xv.w * w3;
        }
    }
#pragma unroll
    for (int j = 0; j < RPT; j++) {
        if (r + j < M) out[(size_t)(r + j) * NOUT + col] = acc[j];
    }
}

// ---------------- Feature-split SpMM (F=64, bf16 gather) ----------------
// Blocks [0,NBH): feature half 0 (cols 0-31). Blocks [NBH,2*NBH): half 1 (cols 32-63).
// Each half's gather footprint is 3.2 MB -> per-XCD-L2 resident; each gather = one 64B line.
// 32 threads per row, 8 rows per block; per-lane loop bounds (exec-mask handles divergence),
// so each wave runs 2 adjacent rows' gather chains concurrently.
__global__ __launch_bounds__(256) void spmm64_split_kernel(
    const unsigned short* __restrict__ tmpb, const int* __restrict__ row_ptr,
    const Edge* __restrict__ pairs, const float* __restrict__ bias,
    float* __restrict__ e_out, float* __restrict__ h_out, int M) {
    const int half = (blockIdx.x >= NBH) ? 1 : 0;
    const int rb = (blockIdx.x - half * NBH) * 8;
    const int t = threadIdx.x;
    const int r = rb + (t >> 5);
    if (r >= M) return;
    const int f = half * 32 + (t & 31);

    int e = row_ptr[r];
    const int end = row_ptr[r + 1];
    float acc = 0.f;
    for (; e + 3 < end; e += 4) {
        Edge p0 = pairs[e + 0], p1 = pairs[e + 1], p2 = pairs[e + 2], p3 = pairs[e + 3];
        float g0 = bf2f(tmpb[(size_t)p0.c * 64 + f]);
        float g1 = bf2f(tmpb[(size_t)p1.c * 64 + f]);
        float g2 = bf2f(tmpb[(size_t)p2.c * 64 + f]);
        float g3 = bf2f(tmpb[(size_t)p3.c * 64 + f]);
        acc += p0.w * g0;
        acc += p1.w * g1;
        acc += p2.w * g2;
        acc += p3.w * g3;
    }
    for (; e < end; e++) {
        Edge p = pairs[e];
        acc += p.w * bf2f(tmpb[(size_t)p.c * 64 + f]);
    }
    float v = acc + bias[f];
    e_out[(size_t)r * 64 + f] = v;
    h_out[(size_t)r * 64 + f] = fmaxf(v, 0.f);
}

// ---------------- SpMM (F=16, fp32) fused with log_softmax ----------------
__global__ __launch_bounds__(256) void spmm16_lsm_kernel(const float* __restrict__ tmp,
                                                         const int* __restrict__ row_ptr,
                                                         const Edge* __restrict__ pairs,
                                                         const float* __restrict__ bias,
                                                         float* __restrict__ e5,
                                                         float* __restrict__ out0, int M) {
    const int f = threadIdx.x & 15;
    const int rl = threadIdx.x >> 4;
    const int r = blockIdx.x * 16 + rl;
    if (r >= M) return;

    const int start = row_ptr[r];
    const int end = row_ptr[r + 1];
    float acc = 0.f;
    int e = start;
    for (; e + 3 < end; e += 4) {
        Edge p0 = pairs[e + 0], p1 = pairs[e + 1], p2 = pairs[e + 2], p3 = pairs[e + 3];
        acc += p0.w * tmp[(size_t)p0.c * 16 + f];
        acc += p1.w * tmp[(size_t)p1.c * 16 + f];
        acc += p2.w * tmp[(size_t)p2.c * 16 + f];
        acc += p3.w * tmp[(size_t)p3.c * 16 + f];
    }
    for (; e < end; e++) {
        Edge p = pairs[e];
        acc += p.w * tmp[(size_t)p.c * 16 + f];
    }
    float v = acc + bias[f];
    e5[(size_t)r * 16 + f] = v;

    float m = v;
#pragma unroll
    for (int off = 1; off < 16; off <<= 1) m = fmaxf(m, __shfl_xor(m, off, 16));
    float s = expf(v - m);
#pragma unroll
    for (int off = 1; off < 16; off <<= 1) s += __shfl_xor(s, off, 16);
    float ls = logf(s);
    out0[(size_t)r * 16 + f] = v - m - ls;
}

// ---------------- launch ----------------

extern "C" void kernel_launch(void* const* d_in, const int* in_sizes, int n_in,
                              void* d_out, int out_size, void* d_ws, size_t ws_size,
                              hipStream_t stream) {
    const float* x = (const float*)d_in[0];
    const int* erow = (const int*)d_in[1];
    const int* ecol = (const int*)d_in[2];
    const float* ew = (const float*)d_in[3];
    const float* W1 = (const float*)d_in[4];
    const float* b1 = (const float*)d_in[5];
    const float* W2 = (const float*)d_in[6];
    const float* b2 = (const float*)d_in[7];
    const float* W3 = (const float*)d_in[8];
    const float* b3 = (const float*)d_in[9];
    const float* W4 = (const float*)d_in[10];
    const float* b4 = (const float*)d_in[11];
    const float* W5 = (const float*)d_in[12];
    const float* b5 = (const float*)d_in[13];

    // Output layout: log_softmax(e5), e1, e2, e3, e4, e5
    float* out0 = (float*)d_out;
    float* e1 = out0 + (size_t)NN * NCLASS;
    float* e2 = e1 + (size_t)NN * NHID;
    float* e3 = e2 + (size_t)NN * NHID;
    float* e4 = e3 + (size_t)NN * NHID;
    float* e5 = e4 + (size_t)NN * NHID;

    // Workspace layout
    char* ws = (char*)d_ws;
    unsigned short* tmpb = (unsigned short*)ws; ws += (size_t)NN * NHID * 2;   // 6.4 MB
    float* tmp32 = (float*)ws; ws += (size_t)NN * NCLASS * sizeof(float);      // 3.2 MB
    float* h = (float*)ws;     ws += (size_t)NN * NHID * sizeof(float);        // 12.8 MB
    int* deg = (int*)ws;       ws += ((size_t)NN * 4 + 255) / 256 * 256;
    int* row_ptr = (int*)ws;   ws += ((size_t)(NN + 1) * 4 + 255) / 256 * 256;
    int* cursor = (int*)ws;    ws += ((size_t)NN * 4 + 255) / 256 * 256;
    int* blocksum = (int*)ws;  ws += ((size_t)NB_SCAN * 4 + 255) / 256 * 256;
    Edge* pairs = (Edge*)ws;   ws += (size_t)NE * sizeof(Edge);                // 6.4 MB

    // ---- CSR build ----
    hipMemsetAsync(deg, 0, (size_t)NN * sizeof(int), stream);
    hist_kernel<<<(NE + 255) / 256, 256, 0, stream>>>(erow, deg, NE);
    scan_sum_kernel<<<NB_SCAN, 256, 0, stream>>>(deg, blocksum, NN);
    scan_top_kernel<<<1, 256, 0, stream>>>(blocksum, NB_SCAN);
    scan_final_kernel<<<NB_SCAN, 256, 0, stream>>>(deg, blocksum, row_ptr, cursor, NN);
    scatter_part_kernel<<<8 * SCHUNKS, 256, 0, stream>>>(erow, ecol, ew, cursor, pairs, NE);

    // ---- Layer 1 ----
    gemm64_kernel<NFEAT, true><<<GB, 256, 0, stream>>>(x, W1, tmpb, NN);
    spmm64_split_kernel<<<2 * NBH, 256, 0, stream>>>(tmpb, row_ptr, pairs, b1, e1, h, NN);

    // ---- Layer 2 ----
    gemm64_kernel<NHID, true><<<GB, 256, 0, stream>>>(h, W2, tmpb, NN);
    spmm64_split_kernel<<<2 * NBH, 256, 0, stream>>>(tmpb, row_ptr, pairs, b2, e2, h, NN);

    // ---- Layer 3 ----
    gemm64_kernel<NHID, true><<<GB, 256, 0, stream>>>(h, W3, tmpb, NN);
    spmm64_split_kernel<<<2 * NBH, 256, 0, stream>>>(tmpb, row_ptr, pairs, b3, e3, h, NN);

    // ---- Layer 4 ----
    gemm64_kernel<NHID, true><<<GB, 256, 0, stream>>>(h, W4, tmpb, NN);
    spmm64_split_kernel<<<2 * NBH, 256, 0, stream>>>(tmpb, row_ptr, pairs, b4, e4, h, NN);

    // ---- Layer 5: GEMM (fp32) -> SpMM fused with log_softmax ----
    gemm_kernel<NHID, NCLASS, 4><<<GB, 256, 0, stream>>>(h, W5, tmp32, NN);
    spmm16_lsm_kernel<<<(NN + 15) / 16, 256, 0, stream>>>(tmp32, row_ptr, pairs, b5, e5, out0, NN);
}

// Round 7
// 395.144 us; speedup vs baseline: 1.1414x; 1.1414x over previous
//
#include <hip/hip_runtime.h>
#include <math.h>

// Problem constants (from reference)
#define NN 50000
#define NE 800000
#define NFEAT 128
#define NHID 64
#define NCLASS 16
#define NB_SCAN ((NN + 255) / 256)  // 196
#define ROWS_PER_GRP 6250           // NN / 8 XCD row-groups
#define GB ((NN + 63) / 64)         // 782 row-tiles
#define BKT_CAP 115000              // per-bucket capacity (expect ~100k +- 3k)
#define NCHUNK 56                   // phase-B chunks per bucket; grid 8*56

struct alignas(8) Edge {
    int c;
    float w;
};

// fp32 <-> bf16 helpers (RNE round)
__device__ inline unsigned short f2bf(float f) {
    unsigned u = __builtin_bit_cast(unsigned, f);
    u += 0x7fffu + ((u >> 16) & 1u);
    return (unsigned short)(u >> 16);
}
__device__ inline float bf2f(unsigned short h) {
    return __builtin_bit_cast(float, (unsigned)h << 16);
}

// ---------------- CSR build ----------------

// Phase A: degree histogram + partition edges into 8 row-group buckets.
// LDS-staged so each block emits one contiguous run per bucket (coalesced-ish writes).
__global__ __launch_bounds__(256) void bucket_hist_kernel(
    const int* __restrict__ erow, const int* __restrict__ ecol, const float* __restrict__ ew,
    int* __restrict__ deg, int* __restrict__ bktcnt, int* __restrict__ br,
    int* __restrict__ bc, float* __restrict__ bw, int E) {
    __shared__ int lcnt[8];
    __shared__ int lbase[8];
    __shared__ int lpos[256];
    const int t = threadIdx.x;
    const int e = blockIdx.x * 256 + t;
    if (t < 8) lcnt[t] = 0;
    __syncthreads();
    int r = 0, c = 0, g = -1;
    float w = 0.f;
    if (e < E) {
        r = erow[e];
        c = ecol[e];
        w = ew[e];
        atomicAdd(&deg[r], 1);
        g = r / ROWS_PER_GRP;
        lpos[t] = atomicAdd(&lcnt[g], 1);
    }
    __syncthreads();
    if (t < 8) lbase[t] = atomicAdd(&bktcnt[t], lcnt[t]);
    __syncthreads();
    if (e < E) {
        int pos = g * BKT_CAP + lbase[g] + lpos[t];
        br[pos] = r;
        bc[pos] = c;
        bw[pos] = w;
    }
}

__global__ __launch_bounds__(256) void scan_sum_kernel(const int* __restrict__ deg,
                                                       int* __restrict__ blocksum, int n) {
    __shared__ int s[256];
    const int t = threadIdx.x;
    int i = blockIdx.x * 256 + t;
    s[t] = (i < n) ? deg[i] : 0;
    __syncthreads();
#pragma unroll
    for (int off = 128; off > 0; off >>= 1) {
        if (t < off) s[t] += s[t + off];
        __syncthreads();
    }
    if (t == 0) blocksum[blockIdx.x] = s[0];
}

__global__ __launch_bounds__(256) void scan_top_kernel(int* __restrict__ blocksum, int nb) {
    __shared__ int s[256];
    const int t = threadIdx.x;
    int v = (t < nb) ? blocksum[t] : 0;
    s[t] = v;
    __syncthreads();
    for (int off = 1; off < 256; off <<= 1) {
        int u = (t >= off) ? s[t - off] : 0;
        __syncthreads();
        s[t] += u;
        __syncthreads();
    }
    if (t < nb) blocksum[t] = s[t] - v;  // exclusive
}

__global__ __launch_bounds__(256) void scan_final_kernel(const int* __restrict__ deg,
                                                         const int* __restrict__ blocksum,
                                                         int* __restrict__ row_ptr,
                                                         int* __restrict__ cursor, int n) {
    __shared__ int s[256];
    const int t = threadIdx.x;
    int i = blockIdx.x * 256 + t;
    int d = (i < n) ? deg[i] : 0;
    s[t] = d;
    __syncthreads();
    for (int off = 1; off < 256; off <<= 1) {
        int u = (t >= off) ? s[t - off] : 0;
        __syncthreads();
        s[t] += u;
        __syncthreads();
    }
    int excl = blocksum[blockIdx.x] + s[t] - d;
    if (i < n) {
        row_ptr[i] = excl;
        cursor[i] = excl;
        if (i == n - 1) row_ptr[n] = excl + d;
    }
}

// Phase B: per-bucket scatter into CSR. blockIdx%8 = bucket = row-group -> the
// destination slice (~0.8 MB of pairs) stays XCD-L2-local (round-3 lesson).
__global__ __launch_bounds__(256) void scatter_bkt_kernel(const int* __restrict__ bktcnt,
                                                          const int* __restrict__ br,
                                                          const int* __restrict__ bc,
                                                          const float* __restrict__ bw,
                                                          int* __restrict__ cursor,
                                                          Edge* __restrict__ pairs) {
    const int g = blockIdx.x & 7;
    const int chunk = blockIdx.x >> 3;
    const int cnt = bktcnt[g];
    const int CH = (cnt + NCHUNK - 1) / NCHUNK;
    const int lo = chunk * CH;
    const int hi = (lo + CH < cnt) ? lo + CH : cnt;
    const int base = g * BKT_CAP;
    for (int i = lo + threadIdx.x; i < hi; i += 256) {
        int r = br[base + i];
        int pos = atomicAdd(&cursor[r], 1);
        Edge p;
        p.c = bc[base + i];
        p.w = bw[base + i];
        pairs[pos] = p;
    }
}

// ---------------- Tiled GEMM: out[M,64] = in[M,K] @ W[K,64], bf16 or fp32 out ----------------
template <int K, bool BF16OUT>
__global__ __launch_bounds__(256) void gemm64_kernel(const float* __restrict__ in,
                                                     const float* __restrict__ Wg,
                                                     void* __restrict__ outv, int M) {
    constexpr int KC = 64;
    __shared__ float xs[KC][68];
    __shared__ float Ws[KC][64];
    const int t = threadIdx.x;
    const int tx = t % 16;
    const int ty = t / 16;
    const int r0 = blockIdx.x * 64;

    float acc[4][4];
#pragma unroll
    for (int i = 0; i < 4; i++)
#pragma unroll
        for (int j = 0; j < 4; j++) acc[i][j] = 0.f;

    for (int k0 = 0; k0 < K; k0 += KC) {
        for (int i = t * 4; i < KC * 64; i += 1024) {
            *(float4*)&Ws[i / 64][i % 64] = *(const float4*)&Wg[(size_t)k0 * 64 + i];
        }
        {
            const int r = t / 4;
            const int q = t % 4;
            const int gr = r0 + r;
#pragma unroll
            for (int i = 0; i < 4; i++) {
                int k = q * 16 + i * 4;
                float4 v;
                if (gr < M)
                    v = *(const float4*)&in[(size_t)gr * K + k0 + k];
                else
                    v = make_float4(0.f, 0.f, 0.f, 0.f);
                xs[k + 0][r] = v.x;
                xs[k + 1][r] = v.y;
                xs[k + 2][r] = v.z;
                xs[k + 3][r] = v.w;
            }
        }
        __syncthreads();
#pragma unroll 8
        for (int k = 0; k < KC; k++) {
            float4 xv = *(const float4*)&xs[k][ty * 4];
            float4 wv = *(const float4*)&Ws[k][tx * 4];
            acc[0][0] += xv.x * wv.x; acc[0][1] += xv.x * wv.y;
            acc[0][2] += xv.x * wv.z; acc[0][3] += xv.x * wv.w;
            acc[1][0] += xv.y * wv.x; acc[1][1] += xv.y * wv.y;
            acc[1][2] += xv.y * wv.z; acc[1][3] += xv.y * wv.w;
            acc[2][0] += xv.z * wv.x; acc[2][1] += xv.z * wv.y;
            acc[2][2] += xv.z * wv.z; acc[2][3] += xv.z * wv.w;
            acc[3][0] += xv.w * wv.x; acc[3][1] += xv.w * wv.y;
            acc[3][2] += xv.w * wv.z; acc[3][3] += xv.w * wv.w;
        }
        __syncthreads();
    }
#pragma unroll
    for (int i = 0; i < 4; i++) {
        int r = r0 + ty * 4 + i;
        if (r < M) {
            if (BF16OUT) {
                ushort4 u;
                u.x = f2bf(acc[i][0]);
                u.y = f2bf(acc[i][1]);
                u.z = f2bf(acc[i][2]);
                u.w = f2bf(acc[i][3]);
                *(ushort4*)&((unsigned short*)outv)[(size_t)r * 64 + tx * 4] = u;
            } else {
                float4 v;
                v.x = acc[i][0]; v.y = acc[i][1]; v.z = acc[i][2]; v.w = acc[i][3];
                *(float4*)&((float*)outv)[(size_t)r * 64 + tx * 4] = v;
            }
        }
    }
}

// ---------------- Small GEMM (layer 5): out[M,16] = in[M,64] @ W[64,16] ----------------
template <int K, int NOUT, int RPT>
__global__ __launch_bounds__(256) void gemm_kernel(const float* __restrict__ in,
                                                   const float* __restrict__ Wg,
                                                   float* __restrict__ out, int M) {
    __shared__ float Wl[K * NOUT];
    for (int i = threadIdx.x * 4; i < K * NOUT; i += 256 * 4) {
        *(float4*)&Wl[i] = *(const float4*)&Wg[i];
    }
    __syncthreads();

    constexpr int GROUPS = 256 / NOUT;
    constexpr int RPB = GROUPS * RPT;
    const int col = threadIdx.x % NOUT;
    const int grp = threadIdx.x / NOUT;
    const int r = blockIdx.x * RPB + grp * RPT;
    if (r >= M) return;

    float acc[RPT];
#pragma unroll
    for (int j = 0; j < RPT; j++) acc[j] = 0.f;

    const float* pr = in + (size_t)r * K;
#pragma unroll 2
    for (int k = 0; k < K; k += 4) {
        float w0 = Wl[(k + 0) * NOUT + col];
        float w1 = Wl[(k + 1) * NOUT + col];
        float w2 = Wl[(k + 2) * NOUT + col];
        float w3 = Wl[(k + 3) * NOUT + col];
#pragma unroll
        for (int j = 0; j < RPT; j++) {
            float4 xv = *(const float4*)(pr + j * K + k);
            acc[j] += xv.x * w0;
            acc[j] += xv.y * w1;
            acc[j] += xv.z * w2;
            acc[j] += xv.w * w3;
        }
    }
#pragma unroll
    for (int j = 0; j < RPT; j++) {
        if (r + j < M) out[(size_t)(r + j) * NOUT + col] = acc[j];
    }
}

// ---------------- SpMM v2 (F=64, bf16 gather, high MLP) ----------------
// 2 rows per wave (32 lanes/row), lane loads a ushort2 feature-pair (dword),
// manual unroll-8: up to 32 cache lines in flight per wave (4x round-4's 8).
// Same total traffic as round 4: one pass over pairs, 128 B gather per edge.
__global__ __launch_bounds__(256) void spmm64v2_kernel(const unsigned short* __restrict__ tmpb,
                                                       const int* __restrict__ row_ptr,
                                                       const Edge* __restrict__ pairs,
                                                       const float* __restrict__ bias,
                                                       float* __restrict__ e_out,
                                                       float* __restrict__ h_out, int M) {
    const int t = threadIdx.x;
    const int r = blockIdx.x * 8 + (t >> 5);
    if (r >= M) return;
    const int f2 = (t & 31) * 2;

    int e = row_ptr[r];
    const int end = row_ptr[r + 1];
    float a0 = 0.f, a1 = 0.f;
    for (; e + 7 < end; e += 8) {
        Edge p0 = pairs[e + 0], p1 = pairs[e + 1], p2 = pairs[e + 2], p3 = pairs[e + 3];
        Edge p4 = pairs[e + 4], p5 = pairs[e + 5], p6 = pairs[e + 6], p7 = pairs[e + 7];
        unsigned g0 = *(const unsigned*)&tmpb[(size_t)p0.c * 64 + f2];
        unsigned g1 = *(const unsigned*)&tmpb[(size_t)p1.c * 64 + f2];
        unsigned g2 = *(const unsigned*)&tmpb[(size_t)p2.c * 64 + f2];
        unsigned g3 = *(const unsigned*)&tmpb[(size_t)p3.c * 64 + f2];
        unsigned g4 = *(const unsigned*)&tmpb[(size_t)p4.c * 64 + f2];
        unsigned g5 = *(const unsigned*)&tmpb[(size_t)p5.c * 64 + f2];
        unsigned g6 = *(const unsigned*)&tmpb[(size_t)p6.c * 64 + f2];
        unsigned g7 = *(const unsigned*)&tmpb[(size_t)p7.c * 64 + f2];
        a0 += p0.w * bf2f((unsigned short)(g0 & 0xffffu));
        a1 += p0.w * bf2f((unsigned short)(g0 >> 16));
        a0 += p1.w * bf2f((unsigned short)(g1 & 0xffffu));
        a1 += p1.w * bf2f((unsigned short)(g1 >> 16));
        a0 += p2.w * bf2f((unsigned short)(g2 & 0xffffu));
        a1 += p2.w * bf2f((unsigned short)(g2 >> 16));
        a0 += p3.w * bf2f((unsigned short)(g3 & 0xffffu));
        a1 += p3.w * bf2f((unsigned short)(g3 >> 16));
        a0 += p4.w * bf2f((unsigned short)(g4 & 0xffffu));
        a1 += p4.w * bf2f((unsigned short)(g4 >> 16));
        a0 += p5.w * bf2f((unsigned short)(g5 & 0xffffu));
        a1 += p5.w * bf2f((unsigned short)(g5 >> 16));
        a0 += p6.w * bf2f((unsigned short)(g6 & 0xffffu));
        a1 += p6.w * bf2f((unsigned short)(g6 >> 16));
        a0 += p7.w * bf2f((unsigned short)(g7 & 0xffffu));
        a1 += p7.w * bf2f((unsigned short)(g7 >> 16));
    }
    for (; e < end; e++) {
        Edge p = pairs[e];
        unsigned g = *(const unsigned*)&tmpb[(size_t)p.c * 64 + f2];
        a0 += p.w * bf2f((unsigned short)(g & 0xffffu));
        a1 += p.w * bf2f((unsigned short)(g >> 16));
    }
    float v0 = a0 + bias[f2];
    float v1 = a1 + bias[f2 + 1];
    float2 v;
    v.x = v0;
    v.y = v1;
    *(float2*)&e_out[(size_t)r * 64 + f2] = v;
    float2 hv;
    hv.x = fmaxf(v0, 0.f);
    hv.y = fmaxf(v1, 0.f);
    *(float2*)&h_out[(size_t)r * 64 + f2] = hv;
}

// ---------------- SpMM (F=16, fp32) fused with log_softmax ----------------
__global__ __launch_bounds__(256) void spmm16_lsm_kernel(const float* __restrict__ tmp,
                                                         const int* __restrict__ row_ptr,
                                                         const Edge* __restrict__ pairs,
                                                         const float* __restrict__ bias,
                                                         float* __restrict__ e5,
                                                         float* __restrict__ out0, int M) {
    const int f = threadIdx.x & 15;
    const int rl = threadIdx.x >> 4;
    const int r = blockIdx.x * 16 + rl;
    if (r >= M) return;

    const int start = row_ptr[r];
    const int end = row_ptr[r + 1];
    float acc = 0.f;
    int e = start;
    for (; e + 3 < end; e += 4) {
        Edge p0 = pairs[e + 0], p1 = pairs[e + 1], p2 = pairs[e + 2], p3 = pairs[e + 3];
        acc += p0.w * tmp[(size_t)p0.c * 16 + f];
        acc += p1.w * tmp[(size_t)p1.c * 16 + f];
        acc += p2.w * tmp[(size_t)p2.c * 16 + f];
        acc += p3.w * tmp[(size_t)p3.c * 16 + f];
    }
    for (; e < end; e++) {
        Edge p = pairs[e];
        acc += p.w * tmp[(size_t)p.c * 16 + f];
    }
    float v = acc + bias[f];
    e5[(size_t)r * 16 + f] = v;

    float m = v;
#pragma unroll
    for (int off = 1; off < 16; off <<= 1) m = fmaxf(m, __shfl_xor(m, off, 16));
    float s = expf(v - m);
#pragma unroll
    for (int off = 1; off < 16; off <<= 1) s += __shfl_xor(s, off, 16);
    float ls = logf(s);
    out0[(size_t)r * 16 + f] = v - m - ls;
}

// ---------------- launch ----------------

extern "C" void kernel_launch(void* const* d_in, const int* in_sizes, int n_in,
                              void* d_out, int out_size, void* d_ws, size_t ws_size,
                              hipStream_t stream) {
    const float* x = (const float*)d_in[0];
    const int* erow = (const int*)d_in[1];
    const int* ecol = (const int*)d_in[2];
    const float* ew = (const float*)d_in[3];
    const float* W1 = (const float*)d_in[4];
    const float* b1 = (const float*)d_in[5];
    const float* W2 = (const float*)d_in[6];
    const float* b2 = (const float*)d_in[7];
    const float* W3 = (const float*)d_in[8];
    const float* b3 = (const float*)d_in[9];
    const float* W4 = (const float*)d_in[10];
    const float* b4 = (const float*)d_in[11];
    const float* W5 = (const float*)d_in[12];
    const float* b5 = (const float*)d_in[13];

    // Output layout: log_softmax(e5), e1, e2, e3, e4, e5
    float* out0 = (float*)d_out;
    float* e1 = out0 + (size_t)NN * NCLASS;
    float* e2 = e1 + (size_t)NN * NHID;
    float* e3 = e2 + (size_t)NN * NHID;
    float* e4 = e3 + (size_t)NN * NHID;
    float* e5 = e4 + (size_t)NN * NHID;

    // Workspace layout
    char* ws = (char*)d_ws;
    unsigned short* tmpb = (unsigned short*)ws; ws += (size_t)NN * NHID * 2;   // 6.4 MB
    float* tmp32 = (float*)ws; ws += (size_t)NN * NCLASS * sizeof(float);      // 3.2 MB
    float* h = (float*)ws;     ws += (size_t)NN * NHID * sizeof(float);        // 12.8 MB
    int* deg = (int*)ws;       ws += (size_t)NN * 4;                            // zeroed below
    int* bktcnt = (int*)ws;    ws += 256;                                       // zeroed below
    int* row_ptr = (int*)ws;   ws += ((size_t)(NN + 1) * 4 + 255) / 256 * 256;
    int* cursor = (int*)ws;    ws += ((size_t)NN * 4 + 255) / 256 * 256;
    int* blocksum = (int*)ws;  ws += ((size_t)NB_SCAN * 4 + 255) / 256 * 256;
    Edge* pairs = (Edge*)ws;   ws += (size_t)NE * sizeof(Edge);                // 6.4 MB
    int* br = (int*)ws;        ws += (size_t)8 * BKT_CAP * 4;                  // 3.7 MB
    int* bc = (int*)ws;        ws += (size_t)8 * BKT_CAP * 4;                  // 3.7 MB
    float* bw = (float*)ws;    ws += (size_t)8 * BKT_CAP * 4;                  // 3.7 MB

    // ---- CSR build: zero deg+bktcnt (contiguous), bucket+hist, scans, scatter ----
    hipMemsetAsync(deg, 0, (size_t)NN * 4 + 256, stream);
    bucket_hist_kernel<<<(NE + 255) / 256, 256, 0, stream>>>(erow, ecol, ew, deg, bktcnt, br,
                                                             bc, bw, NE);
    scan_sum_kernel<<<NB_SCAN, 256, 0, stream>>>(deg, blocksum, NN);
    scan_top_kernel<<<1, 256, 0, stream>>>(blocksum, NB_SCAN);
    scan_final_kernel<<<NB_SCAN, 256, 0, stream>>>(deg, blocksum, row_ptr, cursor, NN);
    scatter_bkt_kernel<<<8 * NCHUNK, 256, 0, stream>>>(bktcnt, br, bc, bw, cursor, pairs);

    // ---- Layer 1 ----
    gemm64_kernel<NFEAT, true><<<GB, 256, 0, stream>>>(x, W1, tmpb, NN);
    spmm64v2_kernel<<<(NN + 7) / 8, 256, 0, stream>>>(tmpb, row_ptr, pairs, b1, e1, h, NN);

    // ---- Layer 2 ----
    gemm64_kernel<NHID, true><<<GB, 256, 0, stream>>>(h, W2, tmpb, NN);
    spmm64v2_kernel<<<(NN + 7) / 8, 256, 0, stream>>>(tmpb, row_ptr, pairs, b2, e2, h, NN);

    // ---- Layer 3 ----
    gemm64_kernel<NHID, true><<<GB, 256, 0, stream>>>(h, W3, tmpb, NN);
    spmm64v2_kernel<<<(NN + 7) / 8, 256, 0, stream>>>(tmpb, row_ptr, pairs, b3, e3, h, NN);

    // ---- Layer 4 ----
    gemm64_kernel<NHID, true><<<GB, 256, 0, stream>>>(h, W4, tmpb, NN);
    spmm64v2_kernel<<<(NN + 7) / 8, 256, 0, stream>>>(tmpb, row_ptr, pairs, b4, e4, h, NN);

    // ---- Layer 5: GEMM (fp32) -> SpMM fused with log_softmax ----
    gemm_kernel<NHID, NCLASS, 4><<<GB, 256, 0, stream>>>(h, W5, tmp32, NN);
    spmm16_lsm_kernel<<<(NN + 15) / 16, 256, 0, stream>>>(tmp32, row_ptr, pairs, b5, e5, out0, NN);
}

// Round 8
// 360.806 us; speedup vs baseline: 1.2500x; 1.0952x over previous
//
#include <hip/hip_runtime.h>
#include <math.h>

// Problem constants (from reference)
#define NN 50000
#define NE 800000
#define NFEAT 128
#define NHID 64
#define NCLASS 16
#define NB_SCAN ((NN + 255) / 256)  // 196
#define ROWS_PER_GRP 6250           // NN / 8 XCD row-groups
#define GB ((NN + 63) / 64)         // 782 row-tiles
#define SCHUNKS 392                 // scatter chunks; grid = 8*392

struct alignas(8) Edge {
    int c;
    float w;
};

// fp32 <-> bf16 helpers (RNE round)
__device__ inline unsigned short f2bf(float f) {
    unsigned u = __builtin_bit_cast(unsigned, f);
    u += 0x7fffu + ((u >> 16) & 1u);
    return (unsigned short)(u >> 16);
}
__device__ inline float bf2f(unsigned short h) {
    return __builtin_bit_cast(float, (unsigned)h << 16);
}

// ---------------- CSR build ----------------

// Degree histogram; atomicAdd's return value IS the edge's rank within its row.
// Pack (row<<16)|rank (row<50000<2^16, rank = degree < 2^16) -> one coalesced stream.
__global__ __launch_bounds__(256) void hist_rank_kernel(const int* __restrict__ erow,
                                                        int* __restrict__ deg,
                                                        unsigned* __restrict__ rr, int E) {
    int e = blockIdx.x * 256 + threadIdx.x;
    if (e < E) {
        int r = erow[e];
        int k = atomicAdd(&deg[r], 1);
        rr[e] = ((unsigned)r << 16) | (unsigned)k;
    }
}

__global__ __launch_bounds__(256) void scan_sum_kernel(const int* __restrict__ deg,
                                                       int* __restrict__ blocksum, int n) {
    __shared__ int s[256];
    const int t = threadIdx.x;
    int i = blockIdx.x * 256 + t;
    s[t] = (i < n) ? deg[i] : 0;
    __syncthreads();
#pragma unroll
    for (int off = 128; off > 0; off >>= 1) {
        if (t < off) s[t] += s[t + off];
        __syncthreads();
    }
    if (t == 0) blocksum[blockIdx.x] = s[0];
}

__global__ __launch_bounds__(256) void scan_top_kernel(int* __restrict__ blocksum, int nb) {
    __shared__ int s[256];
    const int t = threadIdx.x;
    int v = (t < nb) ? blocksum[t] : 0;
    s[t] = v;
    __syncthreads();
    for (int off = 1; off < 256; off <<= 1) {
        int u = (t >= off) ? s[t - off] : 0;
        __syncthreads();
        s[t] += u;
        __syncthreads();
    }
    if (t < nb) blocksum[t] = s[t] - v;  // exclusive
}

__global__ __launch_bounds__(256) void scan_final_kernel(const int* __restrict__ deg,
                                                         const int* __restrict__ blocksum,
                                                         int* __restrict__ row_ptr, int n) {
    __shared__ int s[256];
    const int t = threadIdx.x;
    int i = blockIdx.x * 256 + t;
    int d = (i < n) ? deg[i] : 0;
    s[t] = d;
    __syncthreads();
    for (int off = 1; off < 256; off <<= 1) {
        int u = (t >= off) ? s[t - off] : 0;
        __syncthreads();
        s[t] += u;
        __syncthreads();
    }
    int excl = blocksum[blockIdx.x] + s[t] - d;
    if (i < n) {
        row_ptr[i] = excl;
        if (i == n - 1) row_ptr[n] = excl + d;
    }
}

// Atomic-free scatter: pos = row_ptr[row] + rank. XCD-partitioned by destination
// (blockIdx&7 = row-group) so each XCD's ~0.8 MB pairs slice stays L2-local; only
// the packed rr stream (3.2 MB) is re-read 8x, col/w touched once per match.
__global__ __launch_bounds__(256) void scatter_rank_kernel(const unsigned* __restrict__ rr,
                                                           const int* __restrict__ ecol,
                                                           const float* __restrict__ ew,
                                                           const int* __restrict__ row_ptr,
                                                           Edge* __restrict__ pairs, int E) {
    const int g = blockIdx.x & 7;
    const int chunk = blockIdx.x >> 3;
    const int CH = (E + SCHUNKS - 1) / SCHUNKS;
    const int lo = chunk * CH;
    const int hi = (lo + CH < E) ? lo + CH : E;
    for (int e = lo + threadIdx.x; e < hi; e += 256) {
        unsigned v = rr[e];
        int r = (int)(v >> 16);
        if (r / ROWS_PER_GRP == g) {
            int pos = row_ptr[r] + (int)(v & 0xffffu);
            Edge p;
            p.c = ecol[e];
            p.w = ew[e];
            pairs[pos] = p;
        }
    }
}

// ---------------- Tiled GEMM: out[M,64] = act(in[M,K]) @ W[K,64] ----------------
// RELU_IN applies relu on load (reads e_k directly from d_out; h never materialized).
template <int K, bool RELU_IN>
__global__ __launch_bounds__(256) void gemm64_kernel(const float* __restrict__ in,
                                                     const float* __restrict__ Wg,
                                                     unsigned short* __restrict__ outb, int M) {
    constexpr int KC = 64;
    __shared__ float xs[KC][68];
    __shared__ float Ws[KC][64];
    const int t = threadIdx.x;
    const int tx = t % 16;
    const int ty = t / 16;
    const int r0 = blockIdx.x * 64;

    float acc[4][4];
#pragma unroll
    for (int i = 0; i < 4; i++)
#pragma unroll
        for (int j = 0; j < 4; j++) acc[i][j] = 0.f;

    for (int k0 = 0; k0 < K; k0 += KC) {
        for (int i = t * 4; i < KC * 64; i += 1024) {
            *(float4*)&Ws[i / 64][i % 64] = *(const float4*)&Wg[(size_t)k0 * 64 + i];
        }
        {
            const int r = t / 4;
            const int q = t % 4;
            const int gr = r0 + r;
#pragma unroll
            for (int i = 0; i < 4; i++) {
                int k = q * 16 + i * 4;
                float4 v;
                if (gr < M)
                    v = *(const float4*)&in[(size_t)gr * K + k0 + k];
                else
                    v = make_float4(0.f, 0.f, 0.f, 0.f);
                if (RELU_IN) {
                    v.x = fmaxf(v.x, 0.f);
                    v.y = fmaxf(v.y, 0.f);
                    v.z = fmaxf(v.z, 0.f);
                    v.w = fmaxf(v.w, 0.f);
                }
                xs[k + 0][r] = v.x;
                xs[k + 1][r] = v.y;
                xs[k + 2][r] = v.z;
                xs[k + 3][r] = v.w;
            }
        }
        __syncthreads();
#pragma unroll 8
        for (int k = 0; k < KC; k++) {
            float4 xv = *(const float4*)&xs[k][ty * 4];
            float4 wv = *(const float4*)&Ws[k][tx * 4];
            acc[0][0] += xv.x * wv.x; acc[0][1] += xv.x * wv.y;
            acc[0][2] += xv.x * wv.z; acc[0][3] += xv.x * wv.w;
            acc[1][0] += xv.y * wv.x; acc[1][1] += xv.y * wv.y;
            acc[1][2] += xv.y * wv.z; acc[1][3] += xv.y * wv.w;
            acc[2][0] += xv.z * wv.x; acc[2][1] += xv.z * wv.y;
            acc[2][2] += xv.z * wv.z; acc[2][3] += xv.z * wv.w;
            acc[3][0] += xv.w * wv.x; acc[3][1] += xv.w * wv.y;
            acc[3][2] += xv.w * wv.z; acc[3][3] += xv.w * wv.w;
        }
        __syncthreads();
    }
#pragma unroll
    for (int i = 0; i < 4; i++) {
        int r = r0 + ty * 4 + i;
        if (r < M) {
            ushort4 u;
            u.x = f2bf(acc[i][0]);
            u.y = f2bf(acc[i][1]);
            u.z = f2bf(acc[i][2]);
            u.w = f2bf(acc[i][3]);
            *(ushort4*)&outb[(size_t)r * 64 + tx * 4] = u;
        }
    }
}

// ---------------- Small GEMM (layer 5): out[M,16] = relu(in[M,64]) @ W[64,16] ----------------
template <int K, int NOUT, int RPT, bool RELU_IN>
__global__ __launch_bounds__(256) void gemm_kernel(const float* __restrict__ in,
                                                   const float* __restrict__ Wg,
                                                   float* __restrict__ out, int M) {
    __shared__ float Wl[K * NOUT];
    for (int i = threadIdx.x * 4; i < K * NOUT; i += 256 * 4) {
        *(float4*)&Wl[i] = *(const float4*)&Wg[i];
    }
    __syncthreads();

    constexpr int GROUPS = 256 / NOUT;
    constexpr int RPB = GROUPS * RPT;
    const int col = threadIdx.x % NOUT;
    const int grp = threadIdx.x / NOUT;
    const int r = blockIdx.x * RPB + grp * RPT;
    if (r >= M) return;

    float acc[RPT];
#pragma unroll
    for (int j = 0; j < RPT; j++) acc[j] = 0.f;

    const float* pr = in + (size_t)r * K;
#pragma unroll 2
    for (int k = 0; k < K; k += 4) {
        float w0 = Wl[(k + 0) * NOUT + col];
        float w1 = Wl[(k + 1) * NOUT + col];
        float w2 = Wl[(k + 2) * NOUT + col];
        float w3 = Wl[(k + 3) * NOUT + col];
#pragma unroll
        for (int j = 0; j < RPT; j++) {
            float4 xv = *(const float4*)(pr + j * K + k);
            if (RELU_IN) {
                xv.x = fmaxf(xv.x, 0.f);
                xv.y = fmaxf(xv.y, 0.f);
                xv.z = fmaxf(xv.z, 0.f);
                xv.w = fmaxf(xv.w, 0.f);
            }
            acc[j] += xv.x * w0;
            acc[j] += xv.y * w1;
            acc[j] += xv.z * w2;
            acc[j] += xv.w * w3;
        }
    }
#pragma unroll
    for (int j = 0; j < RPT; j++) {
        if (r + j < M) out[(size_t)(r + j) * NOUT + col] = acc[j];
    }
}

// ---------------- SpMM (F=64, bf16 gather): e_out = A @ tmpb + bias ----------------
// 2 rows per wave (32 lanes/row), lane loads a ushort2 feature-pair, unroll-8.
// No h output: relu is applied by the next GEMM on load.
__global__ __launch_bounds__(256) void spmm64v2_kernel(const unsigned short* __restrict__ tmpb,
                                                       const int* __restrict__ row_ptr,
                                                       const Edge* __restrict__ pairs,
                                                       const float* __restrict__ bias,
                                                       float* __restrict__ e_out, int M) {
    const int t = threadIdx.x;
    const int r = blockIdx.x * 8 + (t >> 5);
    if (r >= M) return;
    const int f2 = (t & 31) * 2;

    int e = row_ptr[r];
    const int end = row_ptr[r + 1];
    float a0 = 0.f, a1 = 0.f;
    for (; e + 7 < end; e += 8) {
        Edge p0 = pairs[e + 0], p1 = pairs[e + 1], p2 = pairs[e + 2], p3 = pairs[e + 3];
        Edge p4 = pairs[e + 4], p5 = pairs[e + 5], p6 = pairs[e + 6], p7 = pairs[e + 7];
        unsigned g0 = *(const unsigned*)&tmpb[(size_t)p0.c * 64 + f2];
        unsigned g1 = *(const unsigned*)&tmpb[(size_t)p1.c * 64 + f2];
        unsigned g2 = *(const unsigned*)&tmpb[(size_t)p2.c * 64 + f2];
        unsigned g3 = *(const unsigned*)&tmpb[(size_t)p3.c * 64 + f2];
        unsigned g4 = *(const unsigned*)&tmpb[(size_t)p4.c * 64 + f2];
        unsigned g5 = *(const unsigned*)&tmpb[(size_t)p5.c * 64 + f2];
        unsigned g6 = *(const unsigned*)&tmpb[(size_t)p6.c * 64 + f2];
        unsigned g7 = *(const unsigned*)&tmpb[(size_t)p7.c * 64 + f2];
        a0 += p0.w * bf2f((unsigned short)(g0 & 0xffffu));
        a1 += p0.w * bf2f((unsigned short)(g0 >> 16));
        a0 += p1.w * bf2f((unsigned short)(g1 & 0xffffu));
        a1 += p1.w * bf2f((unsigned short)(g1 >> 16));
        a0 += p2.w * bf2f((unsigned short)(g2 & 0xffffu));
        a1 += p2.w * bf2f((unsigned short)(g2 >> 16));
        a0 += p3.w * bf2f((unsigned short)(g3 & 0xffffu));
        a1 += p3.w * bf2f((unsigned short)(g3 >> 16));
        a0 += p4.w * bf2f((unsigned short)(g4 & 0xffffu));
        a1 += p4.w * bf2f((unsigned short)(g4 >> 16));
        a0 += p5.w * bf2f((unsigned short)(g5 & 0xffffu));
        a1 += p5.w * bf2f((unsigned short)(g5 >> 16));
        a0 += p6.w * bf2f((unsigned short)(g6 & 0xffffu));
        a1 += p6.w * bf2f((unsigned short)(g6 >> 16));
        a0 += p7.w * bf2f((unsigned short)(g7 & 0xffffu));
        a1 += p7.w * bf2f((unsigned short)(g7 >> 16));
    }
    for (; e < end; e++) {
        Edge p = pairs[e];
        unsigned g = *(const unsigned*)&tmpb[(size_t)p.c * 64 + f2];
        a0 += p.w * bf2f((unsigned short)(g & 0xffffu));
        a1 += p.w * bf2f((unsigned short)(g >> 16));
    }
    float2 v;
    v.x = a0 + bias[f2];
    v.y = a1 + bias[f2 + 1];
    *(float2*)&e_out[(size_t)r * 64 + f2] = v;
}

// ---------------- SpMM (F=16, fp32) fused with log_softmax ----------------
__global__ __launch_bounds__(256) void spmm16_lsm_kernel(const float* __restrict__ tmp,
                                                         const int* __restrict__ row_ptr,
                                                         const Edge* __restrict__ pairs,
                                                         const float* __restrict__ bias,
                                                         float* __restrict__ e5,
                                                         float* __restrict__ out0, int M) {
    const int f = threadIdx.x & 15;
    const int rl = threadIdx.x >> 4;
    const int r = blockIdx.x * 16 + rl;
    if (r >= M) return;

    const int start = row_ptr[r];
    const int end = row_ptr[r + 1];
    float acc = 0.f;
    int e = start;
    for (; e + 3 < end; e += 4) {
        Edge p0 = pairs[e + 0], p1 = pairs[e + 1], p2 = pairs[e + 2], p3 = pairs[e + 3];
        acc += p0.w * tmp[(size_t)p0.c * 16 + f];
        acc += p1.w * tmp[(size_t)p1.c * 16 + f];
        acc += p2.w * tmp[(size_t)p2.c * 16 + f];
        acc += p3.w * tmp[(size_t)p3.c * 16 + f];
    }
    for (; e < end; e++) {
        Edge p = pairs[e];
        acc += p.w * tmp[(size_t)p.c * 16 + f];
    }
    float v = acc + bias[f];
    e5[(size_t)r * 16 + f] = v;

    float m = v;
#pragma unroll
    for (int off = 1; off < 16; off <<= 1) m = fmaxf(m, __shfl_xor(m, off, 16));
    float s = expf(v - m);
#pragma unroll
    for (int off = 1; off < 16; off <<= 1) s += __shfl_xor(s, off, 16);
    float ls = logf(s);
    out0[(size_t)r * 16 + f] = v - m - ls;
}

// ---------------- launch ----------------

extern "C" void kernel_launch(void* const* d_in, const int* in_sizes, int n_in,
                              void* d_out, int out_size, void* d_ws, size_t ws_size,
                              hipStream_t stream) {
    const float* x = (const float*)d_in[0];
    const int* erow = (const int*)d_in[1];
    const int* ecol = (const int*)d_in[2];
    const float* ew = (const float*)d_in[3];
    const float* W1 = (const float*)d_in[4];
    const float* b1 = (const float*)d_in[5];
    const float* W2 = (const float*)d_in[6];
    const float* b2 = (const float*)d_in[7];
    const float* W3 = (const float*)d_in[8];
    const float* b3 = (const float*)d_in[9];
    const float* W4 = (const float*)d_in[10];
    const float* b4 = (const float*)d_in[11];
    const float* W5 = (const float*)d_in[12];
    const float* b5 = (const float*)d_in[13];

    // Output layout: log_softmax(e5), e1, e2, e3, e4, e5
    float* out0 = (float*)d_out;
    float* e1 = out0 + (size_t)NN * NCLASS;
    float* e2 = e1 + (size_t)NN * NHID;
    float* e3 = e2 + (size_t)NN * NHID;
    float* e4 = e3 + (size_t)NN * NHID;
    float* e5 = e4 + (size_t)NN * NHID;

    // Workspace layout
    char* ws = (char*)d_ws;
    unsigned short* tmpb = (unsigned short*)ws; ws += (size_t)NN * NHID * 2;   // 6.4 MB
    float* tmp32 = (float*)ws; ws += (size_t)NN * NCLASS * sizeof(float);      // 3.2 MB
    int* deg = (int*)ws;       ws += ((size_t)NN * 4 + 255) / 256 * 256;       // zeroed below
    int* row_ptr = (int*)ws;   ws += ((size_t)(NN + 1) * 4 + 255) / 256 * 256;
    int* blocksum = (int*)ws;  ws += ((size_t)NB_SCAN * 4 + 255) / 256 * 256;
    unsigned* rr = (unsigned*)ws; ws += (size_t)NE * 4;                        // 3.2 MB
    Edge* pairs = (Edge*)ws;   ws += (size_t)NE * sizeof(Edge);                // 6.4 MB

    // ---- CSR build: hist+rank, scans, atomic-free partitioned scatter ----
    hipMemsetAsync(deg, 0, (size_t)NN * 4, stream);
    hist_rank_kernel<<<(NE + 255) / 256, 256, 0, stream>>>(erow, deg, rr, NE);
    scan_sum_kernel<<<NB_SCAN, 256, 0, stream>>>(deg, blocksum, NN);
    scan_top_kernel<<<1, 256, 0, stream>>>(blocksum, NB_SCAN);
    scan_final_kernel<<<NB_SCAN, 256, 0, stream>>>(deg, blocksum, row_ptr, NN);
    scatter_rank_kernel<<<8 * SCHUNKS, 256, 0, stream>>>(rr, ecol, ew, row_ptr, pairs, NE);

    // ---- Layer 1 ----
    gemm64_kernel<NFEAT, false><<<GB, 256, 0, stream>>>(x, W1, tmpb, NN);
    spmm64v2_kernel<<<(NN + 7) / 8, 256, 0, stream>>>(tmpb, row_ptr, pairs, b1, e1, NN);

    // ---- Layer 2 (reads e1 with relu-on-load) ----
    gemm64_kernel<NHID, true><<<GB, 256, 0, stream>>>(e1, W2, tmpb, NN);
    spmm64v2_kernel<<<(NN + 7) / 8, 256, 0, stream>>>(tmpb, row_ptr, pairs, b2, e2, NN);

    // ---- Layer 3 ----
    gemm64_kernel<NHID, true><<<GB, 256, 0, stream>>>(e2, W3, tmpb, NN);
    spmm64v2_kernel<<<(NN + 7) / 8, 256, 0, stream>>>(tmpb, row_ptr, pairs, b3, e3, NN);

    // ---- Layer 4 ----
    gemm64_kernel<NHID, true><<<GB, 256, 0, stream>>>(e3, W4, tmpb, NN);
    spmm64v2_kernel<<<(NN + 7) / 8, 256, 0, stream>>>(tmpb, row_ptr, pairs, b4, e4, NN);

    // ---- Layer 5: GEMM (fp32, relu-on-load) -> SpMM fused with log_softmax ----
    gemm_kernel<NHID, NCLASS, 4, true><<<GB, 256, 0, stream>>>(e4, W5, tmp32, NN);
    spmm16_lsm_kernel<<<(NN + 15) / 16, 256, 0, stream>>>(tmp32, row_ptr, pairs, b5, e5, out0, NN);
}